// Round 2
// baseline (498.875 us; speedup 1.0000x reference)
//
#include <hip/hip_runtime.h>
#include <cstdint>

#define NB 8
#define NA 100000
#define NC 80
#define TOPN 1000
#define MAXOBJ 100
#define CAND1 16384   // prefilter candidate cap per image
#define SORTN 2048    // final sort size
#define MIN_SCORE 0.05f
#define NMS_THR 0.5f

// ---------------- K1: per-anchor max/argmax + prefilter append ----------------
// Block = 320 threads handles 64 anchors (1280 float4). 4 coalesced float4/thread.
// LDS stride 21 -> conflict-free reduce. Wave 0 appends candidates >= 0.999.
__global__ __launch_bounds__(320) void k_scores(const float* __restrict__ cls,
                                                unsigned int* __restrict__ keys,
                                                int* __restrict__ clsid,
                                                unsigned long long* __restrict__ cand,
                                                unsigned int* __restrict__ n_cand) {
    __shared__ float sval[64 * 21];
    __shared__ int sidx[64 * 21];
    const int b = blockIdx.y;
    const int a0 = blockIdx.x * 64;
    const int t = threadIdx.x;
    const float4* base = (const float4*)(cls + ((size_t)b * NA + a0) * NC);
    const int fmax = (NA - a0) * 20 - 1;

    int f0 = t, f1 = 320 + t, f2 = 640 + t, f3 = 960 + t;
    float4 v0 = base[min(f0, fmax)];
    float4 v1 = base[min(f1, fmax)];
    float4 v2 = base[min(f2, fmax)];
    float4 v3 = base[min(f3, fmax)];

#define REDUCE4(v, f)                                                   \
    {                                                                   \
        float m = v.x; int ix = 0;                                      \
        if (v.y > m) { m = v.y; ix = 1; }                               \
        if (v.z > m) { m = v.z; ix = 2; }                               \
        if (v.w > m) { m = v.w; ix = 3; }                               \
        int al = (f) / 20, e = (f) % 20;                                \
        sval[al * 21 + e] = m;                                          \
        sidx[al * 21 + e] = e * 4 + ix;                                 \
    }
    REDUCE4(v0, f0) REDUCE4(v1, f1) REDUCE4(v2, f2) REDUCE4(v3, f3)
#undef REDUCE4
    __syncthreads();

    if (t < 64) {
        const int a = a0 + t;
        unsigned int key = 0u;
        if (a < NA) {
            float vm = sval[t * 21]; int vi = sidx[t * 21];
            for (int j = 1; j < 20; ++j) {
                float x = sval[t * 21 + j];
                if (x > vm) { vm = x; vi = sidx[t * 21 + j]; }
            }
            key = (vm > MIN_SCORE) ? __float_as_uint(vm) : 0u;
            size_t o = (size_t)b * NA + a;
            keys[o] = key;
            clsid[o] = vi;
        }
        // prefilter: append anchors with score >= 0.999 (expected ~7.7k/image)
        const unsigned int T0 = __float_as_uint(0.999f);
        bool w = (a < NA) && (key >= T0);
        unsigned long long m = __ballot(w);
        if (m) {
            int leader = (int)__builtin_ctzll(m);
            unsigned int bs = 0;
            if (t == leader) bs = atomicAdd(&n_cand[b], (unsigned int)__popcll(m));
            bs = __shfl(bs, leader);
            unsigned int pos = bs + (unsigned int)__popcll(m & ((1ull << t) - 1ull));
            if (w && pos < CAND1)
                cand[(size_t)b * CAND1 + pos] =
                    ((unsigned long long)key << 32) |
                    (unsigned long long)(0xFFFFFFFFu - (unsigned int)a);
        }
    }
}

// wave-aggregated LDS histogram add (for concentrated bins)
__device__ inline void wave_agg_hist(unsigned int* lh, int bin, bool pred) {
    unsigned long long active = __ballot(pred);
    const int lane = threadIdx.x & 63;
    while (active) {
        int leader = (int)__builtin_ctzll(active);
        int lbin = __shfl(bin, leader);
        unsigned long long mask = __ballot(pred && (bin == lbin));
        if (lane == leader) atomicAdd(&lh[lbin], (unsigned int)__popcll(mask));
        active &= ~mask;
    }
}

// one wave: suffix-scan threshold search over LDS histogram
__device__ inline void top_threshold(const unsigned int* lh, int nbins, int minbin,
                                     unsigned int rank, int* out_bin, unsigned int* out_above) {
    const int lane = threadIdx.x;  // caller guarantees tid < 64
    const int chunk = nbins >> 6;
    const int hi = nbins - 1 - lane * chunk;
    const int lo = hi - chunk + 1;
    unsigned int s = 0;
    for (int i = hi; i >= lo; --i)
        if (i >= minbin) s += lh[i];
    unsigned int incl = s;
    for (int d = 1; d < 64; d <<= 1) {
        unsigned int o = __shfl_up(incl, d);
        if (lane >= d) incl += o;
    }
    unsigned int pre = incl - s;
    bool hit = (pre < rank) && (incl >= rank);
    unsigned long long m = __ballot(hit);
    if (m == 0ull) {
        if (lane == 0) { *out_bin = -1; *out_above = 0; }
        return;
    }
    if (hit) {
        unsigned int cum = pre;
        int fb = -1;
        for (int i = hi; i >= lo; --i) {
            if (i < minbin) break;
            unsigned int c = lh[i];
            if (cum + c >= rank) { fb = i; break; }
            cum += c;
        }
        *out_bin = fb;
        *out_above = cum;
    }
}

// ---------------- K2: exact top-1000 select + sort + decode + NMS + output ----------------
// Fast path: radix over the ~7.7k-candidate list (L2-hot). Slow path (candidate
// underflow/overflow, never on this bench): identical radix over full keys[].
__global__ __launch_bounds__(1024) void k_select(
    const unsigned int* __restrict__ keys, const int* __restrict__ clsid,
    const unsigned long long* __restrict__ cand, const unsigned int* __restrict__ n_cand,
    const float* __restrict__ reg, const float* __restrict__ anch,
    float* __restrict__ out) {
    __shared__ unsigned int lh[2048];
    __shared__ unsigned long long sk[SORTN];
    __shared__ float4 sbox[TOPN];
    __shared__ float ss[TOPN];
    __shared__ float scl[TOPN];
    __shared__ int s_bin;
    __shared__ unsigned int s_above;
    __shared__ unsigned int s_cnt;

    const int b = blockIdx.x;
    const int tid = threadIdx.x;
    const int lane = tid & 63;
    const unsigned int* kb = keys + (size_t)b * NA;
    const unsigned long long* cb = cand + (size_t)b * CAND1;
    float* out_s = out + b * MAXOBJ;
    float* out_c = out + NB * MAXOBJ + b * MAXOBJ;
    float* out_b = out + 2 * NB * MAXOBJ + b * MAXOBJ * 4;

    if (tid < MAXOBJ) { out_s[tid] = -1.0f; out_c[tid] = -1.0f; }
    if (tid < MAXOBJ * 4) out_b[tid] = 0.0f;

    const unsigned int n0 = n_cand[b];
    const bool fast = (n0 >= TOPN) && (n0 <= CAND1);
    const int N = fast ? (int)n0 : NA;

    // ---- radix pass 1: bins = key >> 21 (concentrated -> wave-aggregated) ----
    for (int i = tid; i < 2048; i += 1024) lh[i] = 0;
    __syncthreads();
    for (int base = 0; base < N; base += 1024) {
        int i = base + tid;
        unsigned int k = 0u;
        if (i < N) k = fast ? (unsigned int)(cb[i] >> 32) : kb[i];
        wave_agg_hist(lh, (int)(k >> 21), (i < N) && (k != 0u));
    }
    __syncthreads();
    if (tid < 64) top_threshold(lh, 2048, 1, TOPN, &s_bin, &s_above);
    __syncthreads();
    const int p1 = s_bin;
    const unsigned int above1 = s_above;

    unsigned int T;
    if (p1 < 0) {
        T = 1u;  // fewer than TOPN valid: take all nonzero
    } else {
        // ---- pass 2: bits[20:10] within bin p1 (spread -> plain atomics) ----
        __syncthreads();
        for (int i = tid; i < 2048; i += 1024) lh[i] = 0;
        __syncthreads();
        for (int base = 0; base < N; base += 1024) {
            int i = base + tid;
            if (i < N) {
                unsigned int k = fast ? (unsigned int)(cb[i] >> 32) : kb[i];
                if ((int)(k >> 21) == p1) atomicAdd(&lh[(k >> 10) & 0x7FFu], 1u);
            }
        }
        __syncthreads();
        if (tid < 64) top_threshold(lh, 2048, 0, TOPN - above1, &s_bin, &s_above);
        __syncthreads();
        const int p2 = s_bin;
        const unsigned int above2 = above1 + s_above;
        if (p2 < 0) {
            T = 1u;
        } else {
            // ---- pass 3: low 10 bits within (p1,p2) ----
            const unsigned int pref = ((unsigned int)p1 << 11) | (unsigned int)p2;
            __syncthreads();
            for (int i = tid; i < 1024; i += 1024) lh[i] = 0;
            __syncthreads();
            for (int base = 0; base < N; base += 1024) {
                int i = base + tid;
                if (i < N) {
                    unsigned int k = fast ? (unsigned int)(cb[i] >> 32) : kb[i];
                    if ((k >> 10) == pref) atomicAdd(&lh[k & 0x3FFu], 1u);
                }
            }
            __syncthreads();
            if (tid < 64) top_threshold(lh, 1024, 0, TOPN - above2, &s_bin, &s_above);
            __syncthreads();
            T = (s_bin < 0) ? 1u : ((pref << 10) | (unsigned int)s_bin);
        }
    }
    __syncthreads();

    // ---- collect entries >= T (ballot-compacted) ----
    for (int i = tid; i < SORTN; i += 1024) sk[i] = 0ull;
    if (tid == 0) s_cnt = 0;
    __syncthreads();
    for (int base = 0; base < N; base += 1024) {
        int i = base + tid;
        unsigned long long e = 0ull;
        unsigned int k = 0u;
        if (i < N) {
            if (fast) { e = cb[i]; k = (unsigned int)(e >> 32); }
            else {
                k = kb[i];
                e = ((unsigned long long)k << 32) |
                    (unsigned long long)(0xFFFFFFFFu - (unsigned int)i);
            }
        }
        bool w = (k >= T) && (k != 0u);
        unsigned long long m = __ballot(w);
        if (m) {
            int leader = (int)__builtin_ctzll(m);
            unsigned int bs = 0;
            if (lane == leader) bs = atomicAdd(&s_cnt, (unsigned int)__popcll(m));
            bs = __shfl(bs, leader);
            unsigned int pos = bs + (unsigned int)__popcll(m & ((1ull << lane) - 1ull));
            if (w && pos < SORTN) sk[pos] = e;
        }
    }
    __syncthreads();

    // ---- bitonic sort SORTN, descending ----
    for (int k = 2; k <= SORTN; k <<= 1)
        for (int j = k >> 1; j > 0; j >>= 1) {
            __syncthreads();
            for (int i = tid; i < SORTN; i += 1024) {
                int ixj = i ^ j;
                if (ixj > i) {
                    unsigned long long x = sk[i], y = sk[ixj];
                    bool desc = ((i & k) == 0);
                    if (desc ? (x < y) : (x > y)) { sk[i] = y; sk[ixj] = x; }
                }
            }
        }
    __syncthreads();

    // ---- decode top TOPN ----
    if (tid < TOPN) {
        unsigned long long e = sk[tid];
        unsigned int key = (unsigned int)(e >> 32);
        if (key != 0u) {
            int a = (int)(0xFFFFFFFFu - (unsigned int)e);
            size_t base = (size_t)b * NA + a;
            float4 r  = ((const float4*)reg)[base];
            float4 an = ((const float4*)anch)[base];
            float aw = an.z - an.x, ah = an.w - an.y;
            float acx = an.x + 0.5f * aw, acy = an.y + 0.5f * ah;
            float pw = expf(r.z) * aw, ph = expf(r.w) * ah;
            float pcx = r.x * aw + acx, pcy = r.y * ah + acy;
            float4 bx;
            bx.x = truncf(pcx - 0.5f * pw); bx.y = truncf(pcy - 0.5f * ph);
            bx.z = truncf(pcx + 0.5f * pw); bx.w = truncf(pcy + 0.5f * ph);
            sbox[tid] = bx;
            ss[tid] = __uint_as_float(key);
            scl[tid] = (float)clsid[base];
        } else {
            sbox[tid] = make_float4(0.f, 0.f, 0.f, 0.f);
            ss[tid] = -1.0f;
            scl[tid] = -1.0f;
        }
    }
    __syncthreads();
    if (tid >= 64) return;

    // ---- wave 0: greedy NMS; kept boxes in registers across lanes ----
    float k0x1 = 0, k0y1 = 0, k0x2 = 0, k0y2 = 0, k0a = 0;
    float k1x1 = 0, k1y1 = 0, k1x2 = 0, k1y2 = 0, k1a = 0;
    int kc = 0;
    for (int i = 0; i < TOPN; ++i) {
        float4 bi = sbox[i];
        float si = ss[i];
        if (!(si > MIN_SCORE)) break;
        float areai = fmaxf((bi.z - bi.x) * (bi.w - bi.y), 1e-4f);
        bool sup = false;
        if (lane < kc) {
            float ix = fminf(k0x2, bi.z) - fmaxf(k0x1, bi.x);
            float iy = fminf(k0y2, bi.w) - fmaxf(k0y1, bi.y);
            float inter = fmaxf(ix, 0.0f) * fmaxf(iy, 0.0f);
            float uni = fmaxf(k0a + areai - inter, 1e-4f);
            sup = (inter / uni) >= NMS_THR;
        }
        if (lane + 64 < kc) {
            float ix = fminf(k1x2, bi.z) - fmaxf(k1x1, bi.x);
            float iy = fminf(k1y2, bi.w) - fmaxf(k1y1, bi.y);
            float inter = fmaxf(ix, 0.0f) * fmaxf(iy, 0.0f);
            float uni = fmaxf(k1a + areai - inter, 1e-4f);
            sup = sup || ((inter / uni) >= NMS_THR);
        }
        if (__ballot(sup) == 0ull) {
            if (lane == 0) {
                out_s[kc] = si;
                out_c[kc] = scl[i];
                out_b[kc * 4 + 0] = bi.x; out_b[kc * 4 + 1] = bi.y;
                out_b[kc * 4 + 2] = bi.z; out_b[kc * 4 + 3] = bi.w;
            }
            if (kc < 64) {
                if (lane == kc) { k0x1 = bi.x; k0y1 = bi.y; k0x2 = bi.z; k0y2 = bi.w; k0a = areai; }
            } else {
                if (lane == kc - 64) { k1x1 = bi.x; k1y1 = bi.y; k1x2 = bi.z; k1y2 = bi.w; k1a = areai; }
            }
            ++kc;
            if (kc >= MAXOBJ) break;
        }
    }
}

extern "C" void kernel_launch(void* const* d_in, const int* in_sizes, int n_in,
                              void* d_out, int out_size, void* d_ws, size_t ws_size,
                              hipStream_t stream) {
    const float* cls  = (const float*)d_in[0];
    const float* reg  = (const float*)d_in[1];
    const float* anch = (const float*)d_in[2];
    float* out = (float*)d_out;
    char* ws = (char*)d_ws;

    unsigned int* keys = (unsigned int*)ws;                          // 3,200,000 B
    int* clsid = (int*)(ws + 3200000);                               // 3,200,000 B
    unsigned long long* cand = (unsigned long long*)(ws + 6400000);  // 8*16384*8 = 1,048,576 B
    unsigned int* n_cand = (unsigned int*)(ws + 7448576);            // 32 B

    hipMemsetAsync(n_cand, 0, 32, stream);

    dim3 gscore((NA + 63) / 64, NB);  // 1563 x 8
    k_scores<<<gscore, 320, 0, stream>>>(cls, keys, clsid, cand, n_cand);
    k_select<<<NB, 1024, 0, stream>>>(keys, clsid, cand, n_cand, reg, anch, out);
}

// Round 3
// 449.816 us; speedup vs baseline: 1.1091x; 1.1091x over previous
//
#include <hip/hip_runtime.h>
#include <cstdint>

#define NB 8
#define NA 100000
#define NC 80
#define TOPN 1000
#define MAXOBJ 100
#define NREG 64        // candidate sub-lists per image (atomic contention spread)
#define REGCAP 256     // entries per sub-list; 64*256 = 16384 slots per image
#define CTRSTRIDE 32   // uints between counters -> each on its own 128B line
#define SORTN 2048     // final sort size
#define MIN_SCORE 0.05f
#define NMS_THR 0.5f

// ---------------- K1: per-anchor max/argmax + prefilter append ----------------
// Block = 320 threads handles 64 anchors (1280 float4). 4 coalesced float4/thread.
// LDS stride 21 -> conflict-free reduce. Wave 0 appends candidates >= 0.999 into
// one of 64 per-image sub-lists (counter per 128B cacheline -> no atomic pileup).
__global__ __launch_bounds__(320) void k_scores(const float* __restrict__ cls,
                                                unsigned int* __restrict__ keys,
                                                int* __restrict__ clsid,
                                                unsigned long long* __restrict__ cand,
                                                unsigned int* __restrict__ n_cand) {
    __shared__ float sval[64 * 21];
    __shared__ int sidx[64 * 21];
    const int b = blockIdx.y;
    const int a0 = blockIdx.x * 64;
    const int t = threadIdx.x;
    const float4* base = (const float4*)(cls + ((size_t)b * NA + a0) * NC);
    const int fmax = (NA - a0) * 20 - 1;

    int f0 = t, f1 = 320 + t, f2 = 640 + t, f3 = 960 + t;
    float4 v0 = base[min(f0, fmax)];
    float4 v1 = base[min(f1, fmax)];
    float4 v2 = base[min(f2, fmax)];
    float4 v3 = base[min(f3, fmax)];

#define REDUCE4(v, f)                                                   \
    {                                                                   \
        float m = v.x; int ix = 0;                                      \
        if (v.y > m) { m = v.y; ix = 1; }                               \
        if (v.z > m) { m = v.z; ix = 2; }                               \
        if (v.w > m) { m = v.w; ix = 3; }                               \
        int al = (f) / 20, e = (f) % 20;                                \
        sval[al * 21 + e] = m;                                          \
        sidx[al * 21 + e] = e * 4 + ix;                                 \
    }
    REDUCE4(v0, f0) REDUCE4(v1, f1) REDUCE4(v2, f2) REDUCE4(v3, f3)
#undef REDUCE4
    __syncthreads();

    if (t < 64) {
        const int a = a0 + t;
        unsigned int key = 0u;
        if (a < NA) {
            float vm = sval[t * 21]; int vi = sidx[t * 21];
            for (int j = 1; j < 20; ++j) {
                float x = sval[t * 21 + j];
                if (x > vm) { vm = x; vi = sidx[t * 21 + j]; }
            }
            key = (vm > MIN_SCORE) ? __float_as_uint(vm) : 0u;
            size_t o = (size_t)b * NA + a;
            keys[o] = key;
            clsid[o] = vi;
        }
        // prefilter: append anchors with score >= 0.999 (expected ~7.7k/image)
        const unsigned int T0 = __float_as_uint(0.999f);
        bool w = (a < NA) && (key >= T0);
        unsigned long long m = __ballot(w);
        if (m) {
            const int r = blockIdx.x & (NREG - 1);
            unsigned int* ctr = n_cand + (size_t)((b << 6) | r) * CTRSTRIDE;
            unsigned long long* creg = cand + ((size_t)((b << 6) | r)) * REGCAP;
            int leader = (int)__builtin_ctzll(m);
            unsigned int bs = 0;
            if (t == leader) bs = atomicAdd(ctr, (unsigned int)__popcll(m));
            bs = __shfl(bs, leader);
            unsigned int pos = bs + (unsigned int)__popcll(m & ((1ull << t) - 1ull));
            if (w && pos < REGCAP)
                creg[pos] =
                    ((unsigned long long)key << 32) |
                    (unsigned long long)(0xFFFFFFFFu - (unsigned int)a);
        }
    }
}

// wave-aggregated LDS histogram add (for concentrated bins)
__device__ inline void wave_agg_hist(unsigned int* lh, int bin, bool pred) {
    unsigned long long active = __ballot(pred);
    const int lane = threadIdx.x & 63;
    while (active) {
        int leader = (int)__builtin_ctzll(active);
        int lbin = __shfl(bin, leader);
        unsigned long long mask = __ballot(pred && (bin == lbin));
        if (lane == leader) atomicAdd(&lh[lbin], (unsigned int)__popcll(mask));
        active &= ~mask;
    }
}

// one wave: suffix-scan threshold search over LDS histogram
__device__ inline void top_threshold(const unsigned int* lh, int nbins, int minbin,
                                     unsigned int rank, int* out_bin, unsigned int* out_above) {
    const int lane = threadIdx.x;  // caller guarantees tid < 64
    const int chunk = nbins >> 6;
    const int hi = nbins - 1 - lane * chunk;
    const int lo = hi - chunk + 1;
    unsigned int s = 0;
    for (int i = hi; i >= lo; --i)
        if (i >= minbin) s += lh[i];
    unsigned int incl = s;
    for (int d = 1; d < 64; d <<= 1) {
        unsigned int o = __shfl_up(incl, d);
        if (lane >= d) incl += o;
    }
    unsigned int pre = incl - s;
    bool hit = (pre < rank) && (incl >= rank);
    unsigned long long m = __ballot(hit);
    if (m == 0ull) {
        if (lane == 0) { *out_bin = -1; *out_above = 0; }
        return;
    }
    if (hit) {
        unsigned int cum = pre;
        int fb = -1;
        for (int i = hi; i >= lo; --i) {
            if (i < minbin) break;
            unsigned int c = lh[i];
            if (cum + c >= rank) { fb = i; break; }
            cum += c;
        }
        *out_bin = fb;
        *out_above = cum;
    }
}

// ---------------- K2: exact top-1000 select + sort + decode + NMS + output ----------------
// Fast path: radix over the 64x256-slot candidate space (L2-hot). Slow path
// (candidate underflow / region overflow, never on this bench): radix over keys[].
__global__ __launch_bounds__(1024) void k_select(
    const unsigned int* __restrict__ keys, const int* __restrict__ clsid,
    const unsigned long long* __restrict__ cand, const unsigned int* __restrict__ n_cand,
    const float* __restrict__ reg, const float* __restrict__ anch,
    float* __restrict__ out) {
    __shared__ unsigned int lh[2048];
    __shared__ unsigned long long sk[SORTN];
    __shared__ float4 sbox[TOPN];
    __shared__ float ss[TOPN];
    __shared__ float scl[TOPN];
    __shared__ unsigned int s_rc[NREG];
    __shared__ int s_bin;
    __shared__ unsigned int s_above;
    __shared__ unsigned int s_cnt;
    __shared__ unsigned int s_tot;
    __shared__ int s_ovf;

    const int b = blockIdx.x;
    const int tid = threadIdx.x;
    const int lane = tid & 63;
    const unsigned int* kb = keys + (size_t)b * NA;
    const unsigned long long* cb = cand + ((size_t)b << 6) * REGCAP;
    float* out_s = out + b * MAXOBJ;
    float* out_c = out + NB * MAXOBJ + b * MAXOBJ;
    float* out_b = out + 2 * NB * MAXOBJ + b * MAXOBJ * 4;

    if (tid < MAXOBJ) { out_s[tid] = -1.0f; out_c[tid] = -1.0f; }
    if (tid < MAXOBJ * 4) out_b[tid] = 0.0f;

    // load 64 region counts; wave 0 computes total + overflow
    if (tid < NREG) {
        unsigned int c = n_cand[(size_t)((b << 6) | tid) * CTRSTRIDE];
        s_rc[tid] = c;
        unsigned int cc = min(c, (unsigned int)REGCAP);
        for (int d = 32; d; d >>= 1) cc += __shfl_down(cc, d);
        unsigned long long om = __ballot(c > REGCAP);
        if (tid == 0) { s_tot = cc; s_ovf = (om != 0ull) ? 1 : 0; }
    }
    __syncthreads();

    const bool fast = (!s_ovf) && (s_tot >= TOPN);
    const int N = fast ? (NREG * REGCAP) : NA;

// fetch one slot: key=0 if invalid
#define FETCH(i, k, e)                                                        \
    {                                                                         \
        (k) = 0u; (e) = 0ull;                                                 \
        if ((i) < N) {                                                        \
            if (fast) {                                                       \
                int rr = (i) >> 8, pp = (i) & (REGCAP - 1);                   \
                if (pp < (int)s_rc[rr]) {                                     \
                    (e) = cb[i]; (k) = (unsigned int)((e) >> 32);             \
                }                                                             \
            } else {                                                          \
                (k) = kb[i];                                                  \
                (e) = ((unsigned long long)(k) << 32) |                       \
                      (unsigned long long)(0xFFFFFFFFu - (unsigned int)(i));  \
            }                                                                 \
        }                                                                     \
    }

    // ---- radix pass 1: bins = key >> 21 (concentrated -> wave-aggregated) ----
    for (int i = tid; i < 2048; i += 1024) lh[i] = 0;
    __syncthreads();
    for (int base = 0; base < N; base += 1024) {
        int i = base + tid;
        unsigned int k; unsigned long long e;
        FETCH(i, k, e)
        (void)e;
        wave_agg_hist(lh, (int)(k >> 21), k != 0u);
    }
    __syncthreads();
    if (tid < 64) top_threshold(lh, 2048, 1, TOPN, &s_bin, &s_above);
    __syncthreads();
    const int p1 = s_bin;
    const unsigned int above1 = s_above;

    unsigned int T;
    if (p1 < 0) {
        T = 1u;  // fewer than TOPN valid: take all nonzero
    } else {
        // ---- pass 2: bits[20:10] within bin p1 (spread -> plain atomics) ----
        __syncthreads();
        for (int i = tid; i < 2048; i += 1024) lh[i] = 0;
        __syncthreads();
        for (int base = 0; base < N; base += 1024) {
            int i = base + tid;
            unsigned int k; unsigned long long e;
            FETCH(i, k, e)
            (void)e;
            if (k != 0u && (int)(k >> 21) == p1) atomicAdd(&lh[(k >> 10) & 0x7FFu], 1u);
        }
        __syncthreads();
        if (tid < 64) top_threshold(lh, 2048, 0, TOPN - above1, &s_bin, &s_above);
        __syncthreads();
        const int p2 = s_bin;
        const unsigned int above2 = above1 + s_above;
        if (p2 < 0) {
            T = 1u;
        } else {
            // ---- pass 3: low 10 bits within (p1,p2) ----
            const unsigned int pref = ((unsigned int)p1 << 11) | (unsigned int)p2;
            __syncthreads();
            for (int i = tid; i < 1024; i += 1024) lh[i] = 0;
            __syncthreads();
            for (int base = 0; base < N; base += 1024) {
                int i = base + tid;
                unsigned int k; unsigned long long e;
                FETCH(i, k, e)
                (void)e;
                if (k != 0u && (k >> 10) == pref) atomicAdd(&lh[k & 0x3FFu], 1u);
            }
            __syncthreads();
            if (tid < 64) top_threshold(lh, 1024, 0, TOPN - above2, &s_bin, &s_above);
            __syncthreads();
            T = (s_bin < 0) ? 1u : ((pref << 10) | (unsigned int)s_bin);
        }
    }
    __syncthreads();

    // ---- collect entries >= T (ballot-compacted) ----
    for (int i = tid; i < SORTN; i += 1024) sk[i] = 0ull;
    if (tid == 0) s_cnt = 0;
    __syncthreads();
    for (int base = 0; base < N; base += 1024) {
        int i = base + tid;
        unsigned int k; unsigned long long e;
        FETCH(i, k, e)
        bool w = (k >= T) && (k != 0u);
        unsigned long long m = __ballot(w);
        if (m) {
            int leader = (int)__builtin_ctzll(m);
            unsigned int bs = 0;
            if (lane == leader) bs = atomicAdd(&s_cnt, (unsigned int)__popcll(m));
            bs = __shfl(bs, leader);
            unsigned int pos = bs + (unsigned int)__popcll(m & ((1ull << lane) - 1ull));
            if (w && pos < SORTN) sk[pos] = e;
        }
    }
    __syncthreads();
#undef FETCH

    // ---- bitonic sort SORTN, descending ----
    for (int k = 2; k <= SORTN; k <<= 1)
        for (int j = k >> 1; j > 0; j >>= 1) {
            __syncthreads();
            for (int i = tid; i < SORTN; i += 1024) {
                int ixj = i ^ j;
                if (ixj > i) {
                    unsigned long long x = sk[i], y = sk[ixj];
                    bool desc = ((i & k) == 0);
                    if (desc ? (x < y) : (x > y)) { sk[i] = y; sk[ixj] = x; }
                }
            }
        }
    __syncthreads();

    // ---- decode top TOPN ----
    if (tid < TOPN) {
        unsigned long long e = sk[tid];
        unsigned int key = (unsigned int)(e >> 32);
        if (key != 0u) {
            int a = (int)(0xFFFFFFFFu - (unsigned int)e);
            size_t base = (size_t)b * NA + a;
            float4 r  = ((const float4*)reg)[base];
            float4 an = ((const float4*)anch)[base];
            float aw = an.z - an.x, ah = an.w - an.y;
            float acx = an.x + 0.5f * aw, acy = an.y + 0.5f * ah;
            float pw = expf(r.z) * aw, ph = expf(r.w) * ah;
            float pcx = r.x * aw + acx, pcy = r.y * ah + acy;
            float4 bx;
            bx.x = truncf(pcx - 0.5f * pw); bx.y = truncf(pcy - 0.5f * ph);
            bx.z = truncf(pcx + 0.5f * pw); bx.w = truncf(pcy + 0.5f * ph);
            sbox[tid] = bx;
            ss[tid] = __uint_as_float(key);
            scl[tid] = (float)clsid[base];
        } else {
            sbox[tid] = make_float4(0.f, 0.f, 0.f, 0.f);
            ss[tid] = -1.0f;
            scl[tid] = -1.0f;
        }
    }
    __syncthreads();
    if (tid >= 64) return;

    // ---- wave 0: greedy NMS; kept boxes in registers across lanes ----
    float k0x1 = 0, k0y1 = 0, k0x2 = 0, k0y2 = 0, k0a = 0;
    float k1x1 = 0, k1y1 = 0, k1x2 = 0, k1y2 = 0, k1a = 0;
    int kc = 0;
    for (int i = 0; i < TOPN; ++i) {
        float4 bi = sbox[i];
        float si = ss[i];
        if (!(si > MIN_SCORE)) break;
        float areai = fmaxf((bi.z - bi.x) * (bi.w - bi.y), 1e-4f);
        bool sup = false;
        if (lane < kc) {
            float ix = fminf(k0x2, bi.z) - fmaxf(k0x1, bi.x);
            float iy = fminf(k0y2, bi.w) - fmaxf(k0y1, bi.y);
            float inter = fmaxf(ix, 0.0f) * fmaxf(iy, 0.0f);
            float uni = fmaxf(k0a + areai - inter, 1e-4f);
            sup = (inter / uni) >= NMS_THR;
        }
        if (lane + 64 < kc) {
            float ix = fminf(k1x2, bi.z) - fmaxf(k1x1, bi.x);
            float iy = fminf(k1y2, bi.w) - fmaxf(k1y1, bi.y);
            float inter = fmaxf(ix, 0.0f) * fmaxf(iy, 0.0f);
            float uni = fmaxf(k1a + areai - inter, 1e-4f);
            sup = sup || ((inter / uni) >= NMS_THR);
        }
        if (__ballot(sup) == 0ull) {
            if (lane == 0) {
                out_s[kc] = si;
                out_c[kc] = scl[i];
                out_b[kc * 4 + 0] = bi.x; out_b[kc * 4 + 1] = bi.y;
                out_b[kc * 4 + 2] = bi.z; out_b[kc * 4 + 3] = bi.w;
            }
            if (kc < 64) {
                if (lane == kc) { k0x1 = bi.x; k0y1 = bi.y; k0x2 = bi.z; k0y2 = bi.w; k0a = areai; }
            } else {
                if (lane == kc - 64) { k1x1 = bi.x; k1y1 = bi.y; k1x2 = bi.z; k1y2 = bi.w; k1a = areai; }
            }
            ++kc;
            if (kc >= MAXOBJ) break;
        }
    }
}

extern "C" void kernel_launch(void* const* d_in, const int* in_sizes, int n_in,
                              void* d_out, int out_size, void* d_ws, size_t ws_size,
                              hipStream_t stream) {
    const float* cls  = (const float*)d_in[0];
    const float* reg  = (const float*)d_in[1];
    const float* anch = (const float*)d_in[2];
    float* out = (float*)d_out;
    char* ws = (char*)d_ws;

    unsigned int* keys = (unsigned int*)ws;                          // 3,200,000 B
    int* clsid = (int*)(ws + 3200000);                               // 3,200,000 B
    unsigned long long* cand = (unsigned long long*)(ws + 6400000);  // 8*64*256*8 = 1,048,576 B
    unsigned int* n_cand = (unsigned int*)(ws + 7448576);            // 8*64*128 = 65,536 B

    hipMemsetAsync(n_cand, 0, (size_t)NB * NREG * CTRSTRIDE * 4, stream);

    dim3 gscore((NA + 63) / 64, NB);  // 1563 x 8
    k_scores<<<gscore, 320, 0, stream>>>(cls, keys, clsid, cand, n_cand);
    k_select<<<NB, 1024, 0, stream>>>(keys, clsid, cand, n_cand, reg, anch, out);
}

// Round 5
// 445.717 us; speedup vs baseline: 1.1193x; 1.0092x over previous
//
#include <hip/hip_runtime.h>
#include <cstdint>

#define NB 8
#define NA 100000
#define NC 80
#define TOPN 1000
#define MAXOBJ 100
#define NREG 64        // candidate sub-lists per image (atomic contention spread)
#define REGCAP 256     // entries per sub-list; 64*256 = 16384 slots per image
#define CTRSTRIDE 32   // uints between counters -> each on its own 128B line
#define SORTN 2048     // final sort size
#define MIN_SCORE 0.05f
#define NMS_THR 0.5f

// ---------------- K1: per-anchor max/argmax + prefilter append ----------------
// 4 lanes cooperate per anchor (80 classes = 20 float4; 5 float4/lane).
// Per instruction: 4 consecutive lanes read 64 contiguous bytes of one anchor,
// 16 anchors per wave -> fully coalesced 64B segments. Register argmax
// (first-index-wins), 2-step shfl_xor group reduce (tie -> smaller index).
// No LDS, no barrier. Per-wave ballot append into 64 per-image sub-lists.
__global__ __launch_bounds__(256) void k_scores(const float* __restrict__ cls,
                                                unsigned int* __restrict__ keys,
                                                int* __restrict__ clsid,
                                                unsigned long long* __restrict__ cand,
                                                unsigned int* __restrict__ n_cand) {
    const int b = blockIdx.y;
    const int t = threadIdx.x;
    const int lane = t & 63;
    const int sub = lane & 3;                    // lane within 4-lane group
    const int a = blockIdx.x * 64 + (t >> 2);    // anchor for this group
    const bool valid = (a < NA);
    const int aa = valid ? a : (NA - 1);

    const float4* p = (const float4*)(cls + ((size_t)b * NA + aa) * NC);

    float vm = -1e30f; int vi = 0x7FFFFFFF;
#pragma unroll
    for (int s = 0; s < 5; ++s) {
        float4 v = p[sub + s * 4];
        int c0 = (sub + s * 4) * 4;
        if (v.x > vm) { vm = v.x; vi = c0; }
        if (v.y > vm) { vm = v.y; vi = c0 + 1; }
        if (v.z > vm) { vm = v.z; vi = c0 + 2; }
        if (v.w > vm) { vm = v.w; vi = c0 + 3; }
    }
    // cross-lane reduce within the 4-lane group: larger max; tie -> smaller idx
#pragma unroll
    for (int d = 1; d < 4; d <<= 1) {
        float ovm = __shfl_xor(vm, d);
        int ovi = __shfl_xor(vi, d);
        if (ovm > vm || (ovm == vm && ovi < vi)) { vm = ovm; vi = ovi; }
    }

    unsigned int key = (vm > MIN_SCORE) ? __float_as_uint(vm) : 0u;
    if (valid && sub == 0) {
        size_t o = (size_t)b * NA + a;
        keys[o] = key;
        clsid[o] = vi;
    }

    // prefilter: append anchors with score >= 0.999 (expected ~7.7k/image)
    const unsigned int T0 = __float_as_uint(0.999f);
    bool w = valid && (sub == 0) && (key >= T0);
    unsigned long long m = __ballot(w);
    if (m) {
        const int r = blockIdx.x & (NREG - 1);
        unsigned int* ctr = n_cand + (size_t)((b << 6) | r) * CTRSTRIDE;
        unsigned long long* creg = cand + ((size_t)((b << 6) | r)) * REGCAP;
        int leader = (int)__builtin_ctzll(m);
        unsigned int bs = 0;
        if (lane == leader) bs = atomicAdd(ctr, (unsigned int)__popcll(m));
        bs = __shfl(bs, leader);
        unsigned int pos = bs + (unsigned int)__popcll(m & ((1ull << lane) - 1ull));
        if (w && pos < REGCAP)
            creg[pos] =
                ((unsigned long long)key << 32) |
                (unsigned long long)(0xFFFFFFFFu - (unsigned int)a);
    }
}

// wave-aggregated LDS histogram add (for concentrated bins)
__device__ inline void wave_agg_hist(unsigned int* lh, int bin, bool pred) {
    unsigned long long active = __ballot(pred);
    const int lane = threadIdx.x & 63;
    while (active) {
        int leader = (int)__builtin_ctzll(active);
        int lbin = __shfl(bin, leader);
        unsigned long long mask = __ballot(pred && (bin == lbin));
        if (lane == leader) atomicAdd(&lh[lbin], (unsigned int)__popcll(mask));
        active &= ~mask;
    }
}

// one wave: suffix-scan threshold search over LDS histogram
__device__ inline void top_threshold(const unsigned int* lh, int nbins, int minbin,
                                     unsigned int rank, int* out_bin, unsigned int* out_above) {
    const int lane = threadIdx.x;  // caller guarantees tid < 64
    const int chunk = nbins >> 6;
    const int hi = nbins - 1 - lane * chunk;
    const int lo = hi - chunk + 1;
    unsigned int s = 0;
    for (int i = hi; i >= lo; --i)
        if (i >= minbin) s += lh[i];
    unsigned int incl = s;
    for (int d = 1; d < 64; d <<= 1) {
        unsigned int o = __shfl_up(incl, d);
        if (lane >= d) incl += o;
    }
    unsigned int pre = incl - s;
    bool hit = (pre < rank) && (incl >= rank);
    unsigned long long m = __ballot(hit);
    if (m == 0ull) {
        if (lane == 0) { *out_bin = -1; *out_above = 0; }
        return;
    }
    if (hit) {
        unsigned int cum = pre;
        int fb = -1;
        for (int i = hi; i >= lo; --i) {
            if (i < minbin) break;
            unsigned int c = lh[i];
            if (cum + c >= rank) { fb = i; break; }
            cum += c;
        }
        *out_bin = fb;
        *out_above = cum;
    }
}

// ---------------- K2: exact top-1000 select + sort + decode + NMS + output ----------------
// Fast path: radix over the 64x256-slot candidate space (L2-hot). Slow path
// (candidate underflow / region overflow, never on this bench): radix over keys[].
__global__ __launch_bounds__(1024) void k_select(
    const unsigned int* __restrict__ keys, const int* __restrict__ clsid,
    const unsigned long long* __restrict__ cand, const unsigned int* __restrict__ n_cand,
    const float* __restrict__ reg, const float* __restrict__ anch,
    float* __restrict__ out) {
    __shared__ unsigned int lh[2048];
    __shared__ unsigned long long sk[SORTN];
    __shared__ float4 sbox[TOPN];
    __shared__ float ss[TOPN];
    __shared__ float scl[TOPN];
    __shared__ unsigned int s_rc[NREG];
    __shared__ int s_bin;
    __shared__ unsigned int s_above;
    __shared__ unsigned int s_cnt;
    __shared__ unsigned int s_tot;
    __shared__ int s_ovf;

    const int b = blockIdx.x;
    const int tid = threadIdx.x;
    const int lane = tid & 63;
    const unsigned int* kb = keys + (size_t)b * NA;
    const unsigned long long* cb = cand + ((size_t)b << 6) * REGCAP;
    float* out_s = out + b * MAXOBJ;
    float* out_c = out + NB * MAXOBJ + b * MAXOBJ;
    float* out_b = out + 2 * NB * MAXOBJ + b * MAXOBJ * 4;

    if (tid < MAXOBJ) { out_s[tid] = -1.0f; out_c[tid] = -1.0f; }
    if (tid < MAXOBJ * 4) out_b[tid] = 0.0f;

    // load 64 region counts; wave 0 computes total + overflow
    if (tid < NREG) {
        unsigned int c = n_cand[(size_t)((b << 6) | tid) * CTRSTRIDE];
        s_rc[tid] = c;
        unsigned int cc = min(c, (unsigned int)REGCAP);
        for (int d = 32; d; d >>= 1) cc += __shfl_down(cc, d);
        unsigned long long om = __ballot(c > REGCAP);
        if (tid == 0) { s_tot = cc; s_ovf = (om != 0ull) ? 1 : 0; }
    }
    __syncthreads();

    const bool fast = (!s_ovf) && (s_tot >= TOPN);
    const int N = fast ? (NREG * REGCAP) : NA;

// fetch one slot: key=0 if invalid
#define FETCH(i, k, e)                                                        \
    {                                                                         \
        (k) = 0u; (e) = 0ull;                                                 \
        if ((i) < N) {                                                        \
            if (fast) {                                                       \
                int rr = (i) >> 8, pp = (i) & (REGCAP - 1);                   \
                if (pp < (int)s_rc[rr]) {                                     \
                    (e) = cb[i]; (k) = (unsigned int)((e) >> 32);             \
                }                                                             \
            } else {                                                          \
                (k) = kb[i];                                                  \
                (e) = ((unsigned long long)(k) << 32) |                       \
                      (unsigned long long)(0xFFFFFFFFu - (unsigned int)(i));  \
            }                                                                 \
        }                                                                     \
    }

    // ---- radix pass 1: bins = key >> 21 (concentrated -> wave-aggregated) ----
    for (int i = tid; i < 2048; i += 1024) lh[i] = 0;
    __syncthreads();
    for (int base = 0; base < N; base += 1024) {
        int i = base + tid;
        unsigned int k; unsigned long long e;
        FETCH(i, k, e)
        (void)e;
        wave_agg_hist(lh, (int)(k >> 21), k != 0u);
    }
    __syncthreads();
    if (tid < 64) top_threshold(lh, 2048, 1, TOPN, &s_bin, &s_above);
    __syncthreads();
    const int p1 = s_bin;
    const unsigned int above1 = s_above;

    unsigned int T;
    if (p1 < 0) {
        T = 1u;  // fewer than TOPN valid: take all nonzero
    } else {
        // ---- pass 2: bits[20:10] within bin p1 (spread -> plain atomics) ----
        __syncthreads();
        for (int i = tid; i < 2048; i += 1024) lh[i] = 0;
        __syncthreads();
        for (int base = 0; base < N; base += 1024) {
            int i = base + tid;
            unsigned int k; unsigned long long e;
            FETCH(i, k, e)
            (void)e;
            if (k != 0u && (int)(k >> 21) == p1) atomicAdd(&lh[(k >> 10) & 0x7FFu], 1u);
        }
        __syncthreads();
        if (tid < 64) top_threshold(lh, 2048, 0, TOPN - above1, &s_bin, &s_above);
        __syncthreads();
        const int p2 = s_bin;
        const unsigned int above2 = above1 + s_above;
        if (p2 < 0) {
            T = 1u;
        } else if (above2 + lh[p2] <= SORTN) {
            // pass-3 skip: everything >= the (p1,p2) bin floor fits in the sort
            // buffer -> exact top-1000 still falls out of the full sort.
            T = (((unsigned int)p1 << 11) | (unsigned int)p2) << 10;
        } else {
            // ---- pass 3: low 10 bits within (p1,p2) ----
            const unsigned int pref = ((unsigned int)p1 << 11) | (unsigned int)p2;
            __syncthreads();
            for (int i = tid; i < 1024; i += 1024) lh[i] = 0;
            __syncthreads();
            for (int base = 0; base < N; base += 1024) {
                int i = base + tid;
                unsigned int k; unsigned long long e;
                FETCH(i, k, e)
                (void)e;
                if (k != 0u && (k >> 10) == pref) atomicAdd(&lh[k & 0x3FFu], 1u);
            }
            __syncthreads();
            if (tid < 64) top_threshold(lh, 1024, 0, TOPN - above2, &s_bin, &s_above);
            __syncthreads();
            T = (s_bin < 0) ? 1u : ((pref << 10) | (unsigned int)s_bin);
        }
    }
    __syncthreads();

    // ---- collect entries >= T (ballot-compacted) ----
    for (int i = tid; i < SORTN; i += 1024) sk[i] = 0ull;
    if (tid == 0) s_cnt = 0;
    __syncthreads();
    for (int base = 0; base < N; base += 1024) {
        int i = base + tid;
        unsigned int k; unsigned long long e;
        FETCH(i, k, e)
        bool w = (k >= T) && (k != 0u);
        unsigned long long m = __ballot(w);
        if (m) {
            int leader = (int)__builtin_ctzll(m);
            unsigned int bs = 0;
            if (lane == leader) bs = atomicAdd(&s_cnt, (unsigned int)__popcll(m));
            bs = __shfl(bs, leader);
            unsigned int pos = bs + (unsigned int)__popcll(m & ((1ull << lane) - 1ull));
            if (w && pos < SORTN) sk[pos] = e;
        }
    }
    __syncthreads();
#undef FETCH

    // ---- bitonic sort SORTN, descending ----
    for (int k = 2; k <= SORTN; k <<= 1)
        for (int j = k >> 1; j > 0; j >>= 1) {
            __syncthreads();
            for (int i = tid; i < SORTN; i += 1024) {
                int ixj = i ^ j;
                if (ixj > i) {
                    unsigned long long x = sk[i], y = sk[ixj];
                    bool desc = ((i & k) == 0);
                    if (desc ? (x < y) : (x > y)) { sk[i] = y; sk[ixj] = x; }
                }
            }
        }
    __syncthreads();

    // ---- decode top TOPN ----
    if (tid < TOPN) {
        unsigned long long e = sk[tid];
        unsigned int key = (unsigned int)(e >> 32);
        if (key != 0u) {
            int a = (int)(0xFFFFFFFFu - (unsigned int)e);
            size_t base = (size_t)b * NA + a;
            float4 r  = ((const float4*)reg)[base];
            float4 an = ((const float4*)anch)[base];
            float aw = an.z - an.x, ah = an.w - an.y;
            float acx = an.x + 0.5f * aw, acy = an.y + 0.5f * ah;
            float pw = expf(r.z) * aw, ph = expf(r.w) * ah;
            float pcx = r.x * aw + acx, pcy = r.y * ah + acy;
            float4 bx;
            bx.x = truncf(pcx - 0.5f * pw); bx.y = truncf(pcy - 0.5f * ph);
            bx.z = truncf(pcx + 0.5f * pw); bx.w = truncf(pcy + 0.5f * ph);
            sbox[tid] = bx;
            ss[tid] = __uint_as_float(key);
            scl[tid] = (float)clsid[base];
        } else {
            sbox[tid] = make_float4(0.f, 0.f, 0.f, 0.f);
            ss[tid] = -1.0f;
            scl[tid] = -1.0f;
        }
    }
    __syncthreads();
    if (tid >= 64) return;

    // ---- wave 0: greedy NMS; kept boxes in registers across lanes ----
    float k0x1 = 0, k0y1 = 0, k0x2 = 0, k0y2 = 0, k0a = 0;
    float k1x1 = 0, k1y1 = 0, k1x2 = 0, k1y2 = 0, k1a = 0;
    int kc = 0;
    for (int i = 0; i < TOPN; ++i) {
        float4 bi = sbox[i];
        float si = ss[i];
        if (!(si > MIN_SCORE)) break;
        float areai = fmaxf((bi.z - bi.x) * (bi.w - bi.y), 1e-4f);
        bool sup = false;
        if (lane < kc) {
            float ix = fminf(k0x2, bi.z) - fmaxf(k0x1, bi.x);
            float iy = fminf(k0y2, bi.w) - fmaxf(k0y1, bi.y);
            float inter = fmaxf(ix, 0.0f) * fmaxf(iy, 0.0f);
            float uni = fmaxf(k0a + areai - inter, 1e-4f);
            sup = (inter / uni) >= NMS_THR;
        }
        if (lane + 64 < kc) {
            float ix = fminf(k1x2, bi.z) - fmaxf(k1x1, bi.x);
            float iy = fminf(k1y2, bi.w) - fmaxf(k1y1, bi.y);
            float inter = fmaxf(ix, 0.0f) * fmaxf(iy, 0.0f);
            float uni = fmaxf(k1a + areai - inter, 1e-4f);
            sup = sup || ((inter / uni) >= NMS_THR);
        }
        if (__ballot(sup) == 0ull) {
            if (lane == 0) {
                out_s[kc] = si;
                out_c[kc] = scl[i];
                out_b[kc * 4 + 0] = bi.x; out_b[kc * 4 + 1] = bi.y;
                out_b[kc * 4 + 2] = bi.z; out_b[kc * 4 + 3] = bi.w;
            }
            if (kc < 64) {
                if (lane == kc) { k0x1 = bi.x; k0y1 = bi.y; k0x2 = bi.z; k0y2 = bi.w; k0a = areai; }
            } else {
                if (lane == kc - 64) { k1x1 = bi.x; k1y1 = bi.y; k1x2 = bi.z; k1y2 = bi.w; k1a = areai; }
            }
            ++kc;
            if (kc >= MAXOBJ) break;
        }
    }
}

extern "C" void kernel_launch(void* const* d_in, const int* in_sizes, int n_in,
                              void* d_out, int out_size, void* d_ws, size_t ws_size,
                              hipStream_t stream) {
    const float* cls  = (const float*)d_in[0];
    const float* reg  = (const float*)d_in[1];
    const float* anch = (const float*)d_in[2];
    float* out = (float*)d_out;
    char* ws = (char*)d_ws;

    unsigned int* keys = (unsigned int*)ws;                          // 3,200,000 B
    int* clsid = (int*)(ws + 3200000);                               // 3,200,000 B
    unsigned long long* cand = (unsigned long long*)(ws + 6400000);  // 8*64*256*8 = 1,048,576 B
    unsigned int* n_cand = (unsigned int*)(ws + 7448576);            // 8*64*128 = 65,536 B

    hipMemsetAsync(n_cand, 0, (size_t)NB * NREG * CTRSTRIDE * 4, stream);

    dim3 gscore((NA + 63) / 64, NB);  // 1563 x 8, 64 anchors/block
    k_scores<<<gscore, 256, 0, stream>>>(cls, keys, clsid, cand, n_cand);
    k_select<<<NB, 1024, 0, stream>>>(keys, clsid, cand, n_cand, reg, anch, out);
}